// Round 7
// baseline (687.447 us; speedup 1.0000x reference)
//
#include <hip/hip_runtime.h>
#include <hip/hip_bf16.h>

#define IN_EPS 1e-5f

typedef __attribute__((ext_vector_type(8))) short short8;
typedef __attribute__((ext_vector_type(4))) float f32x4;

__device__ __forceinline__ short f2bf(float f) {
  __hip_bfloat16 h = (__hip_bfloat16)f;   // lowers to v_cvt_pk_bf16_f32
  return *(short*)&h;
}

// ---------------------------------------------------------------------------
// Weight conversion: f32 [O][C][3][3] -> bf16 FRAGMENT-CONTIGUOUS panel image.
// Panel p = mblk*36 + cb*9 + tap (8192 shorts). Within a panel:
//   slot = (wr<<3)|(mf<<1)|ks   (wr=o>>6&1, mf=(o>>4)&3, ks=cl>>5)
//   lane = (lane_hi<<4)|fr      (lane_hi=(cl>>3)&3, fr=o&15), j = cl&7
//   dst = (p<<13) + (slot<<9) + (lane<<3) + j
// A wave's MFMA A-fragment (per mf,ks) is then 64 lanes x 16B CONTIGUOUS.
// ---------------------------------------------------------------------------
__global__ void wconv_k(const float* __restrict__ src, short* __restrict__ dst,
                        int O) {
  int idx = blockIdx.x * 256 + threadIdx.x;
  if (idx >= O * 2304) return;
  int o = idx / 2304;
  int r = idx - o * 2304;
  int c = r / 9;
  int k = r - c * 9;
  int mblk = o >> 7, ol = o & 127;
  int wr = ol >> 6, mf = (ol >> 4) & 3, fr = ol & 15;
  int cb = c >> 6, cl = c & 63;
  int ks = cl >> 5, lane_hi = (cl >> 3) & 3, j = cl & 7;
  size_t panel = mblk * 36 + cb * 9 + k;
  dst[(panel << 13) + (((wr << 3) | (mf << 1) | ks) << 9) +
      ((((lane_hi << 4) | fr)) << 3) + j] = f2bf(src[idx]);
}

// ---------------------------------------------------------------------------
// Adaptive Gaussian kernel: kern[b][k][h][w] = exp(-0.5 * sum_c dg^2)
// lane == image col; neighbors via shfl; no barriers in the channel loop.
// ---------------------------------------------------------------------------
__global__ __launch_bounds__(256) void kern_k(const float* __restrict__ g,
                                              float* __restrict__ kern) {
  int h = blockIdx.x, b = blockIdx.y;
  int t = threadIdx.x, w = t & 63, cg = t >> 6;
  float acc[9];
#pragma unroll
  for (int k = 0; k < 9; ++k) acc[k] = 0.f;
  const float* base = g + (((size_t)b * 256 + (cg << 6)) << 12) + (h << 6) + w;
#pragma unroll 4
  for (int cc = 0; cc < 64; ++cc) {
    const float* gp = base + ((size_t)cc << 12);
    float mid = gp[0];
    float top = (h > 0) ? gp[-64] : 0.f;
    float bot = (h < 63) ? gp[64] : 0.f;
    float rows[3] = {top, mid, bot};
#pragma unroll
    for (int i = 0; i < 3; ++i) {
      float v = rows[i];
      float l = __shfl_up(v, 1);
      float r = __shfl_down(v, 1);
      if (w == 0) l = 0.f;
      if (w == 63) r = 0.f;
      float dl = l - mid, dm = v - mid, dr = r - mid;
      acc[i * 3 + 0] += dl * dl;
      acc[i * 3 + 1] += dm * dm;
      acc[i * 3 + 2] += dr * dr;
    }
  }
  __shared__ float red[4][9][64];
#pragma unroll
  for (int k = 0; k < 9; ++k) red[cg][k][w] = acc[k];
  __syncthreads();
  for (int idx = t; idx < 576; idx += 256) {
    int k = idx >> 6, w2 = idx & 63;
    float s = red[0][k][w2] + red[1][k][w2] + red[2][k][w2] + red[3][k][w2];
    kern[(((size_t)b * 9 + k) << 12) + (h << 6) + w2] = expf(-0.5f * s);
  }
}

// ---------------------------------------------------------------------------
// Implicit-GEMM conv, tap-reuse, 256 thr / 4 waves (2Mx2N), wave tile 64x64.
// BM=128, BN=128 (2 image rows). K = ncb c-blocks x 9 taps.
// A: NO LDS -- fragment-contiguous panels read straight from global (L1/L2
//    resident, 1KB coalesced per fragment). Only B lives in LDS, so barriers
//    exist only at c-block boundaries (2 per c-block).
// B: halo [4 rows][64 cols][64 ch] bf16, staged once per c-block.
// GEMM1 (USE_KERN): per-mf mini-partial, acc += kern[tap,px]*part (f32).
// GEMM2 (USE_NORM, KSPLIT): norm+relu fused into staging; K split across
//   blockIdx.y, partials to outA / outB.
// ---------------------------------------------------------------------------
template <int MTOT, bool USE_KERN, bool USE_NORM, bool KSPLIT>
__global__ __launch_bounds__(256, 2) void gemm_conv(
    const short* __restrict__ Wimg, const float* __restrict__ X,
    const float* __restrict__ Kf, const float* __restrict__ MRin,
    float* __restrict__ outA, float* __restrict__ outB) {
  __shared__ short ldsB[16384];    // [r 4][col 64][c 64] swizzled, 32KB
  __shared__ short ldsS[512];      // side halo cols (-1,64): zeros, 1KB
  __shared__ float klds[USE_KERN ? 1152 : 1];  // kern f32 [9][128]

  const int t = threadIdx.x;
  const int nblk = blockIdx.x, b = blockIdx.z;
  const int mblk = KSPLIT ? 0 : blockIdx.y;
  const int cb0 = KSPLIT ? (int)blockIdx.y * 2 : 0;
  const int ncb = KSPLIT ? 2 : 4;
  float* __restrict__ outp = (KSPLIT && blockIdx.y) ? outB : outA;
  const int h0 = nblk * 2;
  const int lane = t & 63, wid = t >> 6;
  const int wr = wid >> 1, wc = wid & 1;
  const int fr = lane & 15, kg = (lane >> 4) << 3;
  const int scol = t & 63, c16 = (t >> 6) << 4;   // B staging: col, 16-ch base

  f32x4 acc[4][4];
#pragma unroll
  for (int i = 0; i < 4; ++i)
#pragma unroll
    for (int j = 0; j < 4; ++j) acc[i][j] = {0.f, 0.f, 0.f, 0.f};

  auto stageB = [&](int cbrel) {
    int c0 = ((cb0 + cbrel) << 6) + c16;
    float2 mr[16];
    if (USE_NORM) {
#pragma unroll
      for (int i = 0; i < 16; ++i)
        mr[i] = ((const float2*)MRin)[b * 256 + c0 + i];
    }
#pragma unroll
    for (int r = 0; r < 4; ++r) {
      int hr = h0 - 1 + r;
      bool okr = (unsigned)hr < 64u;
      const float* src = X + (((size_t)b * 256 + c0) << 12) + (hr << 6) + scol;
      short8 pk0, pk1;
#pragma unroll
      for (int i = 0; i < 8; ++i) {
        float x = okr ? src[(size_t)i << 12] : 0.f;
        float y = okr ? src[(size_t)(i + 8) << 12] : 0.f;
        if (USE_NORM) {
          x = fmaxf((x - mr[i].x) * mr[i].y, 0.f);
          y = fmaxf((y - mr[i + 8].x) * mr[i + 8].y, 0.f);
        }
        pk0[i] = f2bf(x);
        pk1[i] = f2bf(y);
      }
      int base = ((r << 6) + scol) << 6;
      *(short8*)&ldsB[base + (c16 ^ ((scol & 7) << 3))] = pk0;
      *(short8*)&ldsB[base + ((c16 + 8) ^ ((scol & 7) << 3))] = pk1;
    }
  };

  auto computeTap = [&](int cbrel, int tap) {
    const int di = tap / 3 - 1, dj = tap % 3 - 1;
    const int rw = wc + di + 1;    // halo row for this wave (uniform)
    const short* Apan = Wimg + ((size_t)(mblk * 36 + (cb0 + cbrel) * 9 + tap) << 13)
                        + (wr << 12) + (lane << 3);
    float kq0, kq1, kq2, kq3;
    if (USE_KERN) {
      kq0 = klds[tap * 128 + (wc << 6) + fr];
      kq1 = klds[tap * 128 + (wc << 6) + 16 + fr];
      kq2 = klds[tap * 128 + (wc << 6) + 32 + fr];
      kq3 = klds[tap * 128 + (wc << 6) + 48 + fr];
    }
    short8 Bf[2][4];
#pragma unroll
    for (int ks = 0; ks < 2; ++ks) {
      int kb = (ks << 5) + kg;
#pragma unroll
      for (int nf = 0; nf < 4; ++nf) {
        int wcol = (nf << 4) + fr + dj;
        int kbs = kb ^ ((wcol & 7) << 3);
        const short* pm = &ldsB[(((rw << 6) + wcol) << 6) + kbs];
        const short* ps = &ldsS[(((rw << 1) + (wcol == 64)) << 6) + kbs];
        Bf[ks][nf] = *(const short8*)(((unsigned)wcol < 64u) ? pm : ps);
      }
    }
#pragma unroll
    for (int mf = 0; mf < 4; ++mf) {
      short8 A0 = *(const short8*)(Apan + ((mf << 1) << 9));
      short8 A1 = *(const short8*)(Apan + (((mf << 1) | 1) << 9));
      __builtin_amdgcn_s_setprio(1);
      if (USE_KERN) {
        f32x4 p0 = {0.f, 0.f, 0.f, 0.f}, p1 = {0.f, 0.f, 0.f, 0.f};
        f32x4 p2 = {0.f, 0.f, 0.f, 0.f}, p3 = {0.f, 0.f, 0.f, 0.f};
        p0 = __builtin_amdgcn_mfma_f32_16x16x32_bf16(A0, Bf[0][0], p0, 0, 0, 0);
        p1 = __builtin_amdgcn_mfma_f32_16x16x32_bf16(A0, Bf[0][1], p1, 0, 0, 0);
        p2 = __builtin_amdgcn_mfma_f32_16x16x32_bf16(A0, Bf[0][2], p2, 0, 0, 0);
        p3 = __builtin_amdgcn_mfma_f32_16x16x32_bf16(A0, Bf[0][3], p3, 0, 0, 0);
        p0 = __builtin_amdgcn_mfma_f32_16x16x32_bf16(A1, Bf[1][0], p0, 0, 0, 0);
        p1 = __builtin_amdgcn_mfma_f32_16x16x32_bf16(A1, Bf[1][1], p1, 0, 0, 0);
        p2 = __builtin_amdgcn_mfma_f32_16x16x32_bf16(A1, Bf[1][2], p2, 0, 0, 0);
        p3 = __builtin_amdgcn_mfma_f32_16x16x32_bf16(A1, Bf[1][3], p3, 0, 0, 0);
        __builtin_amdgcn_s_setprio(0);
#pragma unroll
        for (int j = 0; j < 4; ++j) {
          acc[mf][0][j] += kq0 * p0[j];
          acc[mf][1][j] += kq1 * p1[j];
          acc[mf][2][j] += kq2 * p2[j];
          acc[mf][3][j] += kq3 * p3[j];
        }
      } else {
        acc[mf][0] = __builtin_amdgcn_mfma_f32_16x16x32_bf16(A0, Bf[0][0], acc[mf][0], 0, 0, 0);
        acc[mf][1] = __builtin_amdgcn_mfma_f32_16x16x32_bf16(A0, Bf[0][1], acc[mf][1], 0, 0, 0);
        acc[mf][2] = __builtin_amdgcn_mfma_f32_16x16x32_bf16(A0, Bf[0][2], acc[mf][2], 0, 0, 0);
        acc[mf][3] = __builtin_amdgcn_mfma_f32_16x16x32_bf16(A0, Bf[0][3], acc[mf][3], 0, 0, 0);
        acc[mf][0] = __builtin_amdgcn_mfma_f32_16x16x32_bf16(A1, Bf[1][0], acc[mf][0], 0, 0, 0);
        acc[mf][1] = __builtin_amdgcn_mfma_f32_16x16x32_bf16(A1, Bf[1][1], acc[mf][1], 0, 0, 0);
        acc[mf][2] = __builtin_amdgcn_mfma_f32_16x16x32_bf16(A1, Bf[1][2], acc[mf][2], 0, 0, 0);
        acc[mf][3] = __builtin_amdgcn_mfma_f32_16x16x32_bf16(A1, Bf[1][3], acc[mf][3], 0, 0, 0);
        __builtin_amdgcn_s_setprio(0);
      }
    }
  };

  // ---- prologue ----
  if (t < 64) {
    short8 z = {0, 0, 0, 0, 0, 0, 0, 0};
    *(short8*)&ldsS[t << 3] = z;
  }
  if (USE_KERN) {
    for (int idx = t; idx < 1152; idx += 256) {
      int tap = idx >> 7, px = idx & 127;
      klds[idx] = Kf[(((size_t)b * 9 + tap) << 12) +
                     ((h0 + (px >> 6)) << 6) + (px & 63)];
    }
  }
  stageB(0);
  __syncthreads();   // publishes B / klds / ldsS

  // ---- main loop: ncb c-blocks x 9 taps; barriers only at cb boundaries ----
  for (int cbrel = 0; cbrel < ncb; ++cbrel) {
    if (cbrel) {
      __syncthreads();      // all waves done reading old B
      stageB(cbrel);
      __syncthreads();      // new B visible
    }
#pragma unroll
    for (int tap = 0; tap < 9; ++tap) computeTap(cbrel, tap);
  }

  // ---- epilogue ----
  const int row4 = (lane >> 4) << 2;
#pragma unroll
  for (int mf = 0; mf < 4; ++mf) {
    int o = (mblk << 7) + (wr << 6) + (mf << 4) + row4;
    size_t ob = (((size_t)b * MTOT + o) << 12) + (nblk << 7) + (wc << 6) + fr;
#pragma unroll
    for (int nf = 0; nf < 4; ++nf) {
      f32x4 v = acc[mf][nf];
      size_t oo = ob + (nf << 4);
      outp[oo] = v[0];
      outp[oo + 4096] = v[1];
      outp[oo + 8192] = v[2];
      outp[oo + 12288] = v[3];
    }
  }
}

// ---------------------------------------------------------------------------
// per-(b,ch) mean / rstd over 4096 pixels (single input)
// ---------------------------------------------------------------------------
__global__ __launch_bounds__(256) void reduce_mv(const float* __restrict__ x,
                                                 float* __restrict__ mr) {
  int bc = blockIdx.x, t = threadIdx.x;
  const float4* xp = (const float4*)(x + ((size_t)bc << 12));
  float s = 0.f, s2 = 0.f;
  for (int i = t; i < 1024; i += 256) {
    float4 v = xp[i];
    s += v.x + v.y + v.z + v.w;
    s2 += v.x * v.x + v.y * v.y + v.z * v.z + v.w * v.w;
  }
#pragma unroll
  for (int off = 32; off; off >>= 1) {
    s += __shfl_down(s, off);
    s2 += __shfl_down(s2, off);
  }
  __shared__ float ls[4], ls2[4];
  int wid = t >> 6, lane = t & 63;
  if (!lane) { ls[wid] = s; ls2[wid] = s2; }
  __syncthreads();
  if (!t) {
    s = ls[0] + ls[1] + ls[2] + ls[3];
    s2 = ls2[0] + ls2[1] + ls2[2] + ls2[3];
    float m = s * (1.f / 4096.f);
    float var = s2 * (1.f / 4096.f) - m * m;
    mr[2 * bc] = m;
    mr[2 * bc + 1] = rsqrtf(fmaxf(var, 0.f) + IN_EPS);
  }
}

// ---------------------------------------------------------------------------
// per-(b,ch) mean / rstd over 4096 pixels of (a + b) (split-K partials)
// ---------------------------------------------------------------------------
__global__ __launch_bounds__(256) void reduce_mv2(const float* __restrict__ xa,
                                                  const float* __restrict__ xb,
                                                  float* __restrict__ mr) {
  int bc = blockIdx.x, t = threadIdx.x;
  const float4* ap = (const float4*)(xa + ((size_t)bc << 12));
  const float4* bp = (const float4*)(xb + ((size_t)bc << 12));
  float s = 0.f, s2 = 0.f;
  for (int i = t; i < 1024; i += 256) {
    float4 va = ap[i], vb = bp[i];
    float x0 = va.x + vb.x, x1 = va.y + vb.y, x2 = va.z + vb.z, x3 = va.w + vb.w;
    s += x0 + x1 + x2 + x3;
    s2 += x0 * x0 + x1 * x1 + x2 * x2 + x3 * x3;
  }
#pragma unroll
  for (int off = 32; off; off >>= 1) {
    s += __shfl_down(s, off);
    s2 += __shfl_down(s2, off);
  }
  __shared__ float ls[4], ls2[4];
  int wid = t >> 6, lane = t & 63;
  if (!lane) { ls[wid] = s; ls2[wid] = s2; }
  __syncthreads();
  if (!t) {
    s = ls[0] + ls[1] + ls[2] + ls[3];
    s2 = ls2[0] + ls2[1] + ls2[2] + ls2[3];
    float m = s * (1.f / 4096.f);
    float var = s2 * (1.f / 4096.f) - m * m;
    mr[2 * bc] = m;
    mr[2 * bc + 1] = rsqrtf(fmaxf(var, 0.f) + IN_EPS);
  }
}

// ---------------------------------------------------------------------------
// out = relu(((a+b) - mean)*rstd); a aliases out (read-before-write per elem)
// ---------------------------------------------------------------------------
__global__ __launch_bounds__(256) void finalize2(const float* __restrict__ ya,
                                                 const float* __restrict__ yb,
                                                 const float* __restrict__ mr,
                                                 float* __restrict__ out) {
  int i = blockIdx.x * 256 + threadIdx.x;
  int bc = i >> 10;
  float m = mr[2 * bc], r = mr[2 * bc + 1];
  float4 va = ((const float4*)ya)[i];
  float4 vb = ((const float4*)yb)[i];
  float4 v;
  v.x = fmaxf((va.x + vb.x - m) * r, 0.f);
  v.y = fmaxf((va.y + vb.y - m) * r, 0.f);
  v.z = fmaxf((va.z + vb.z - m) * r, 0.f);
  v.w = fmaxf((va.w + vb.w - m) * r, 0.f);
  ((float4*)out)[i] = v;
}

extern "C" void kernel_launch(void* const* d_in, const int* in_sizes, int n_in,
                              void* d_out, int out_size, void* d_ws,
                              size_t ws_size, hipStream_t stream) {
  (void)in_sizes; (void)n_in; (void)out_size; (void)ws_size;
  const float* feat  = (const float*)d_in[0];
  const float* guide = (const float*)d_in[1];
  const float* pac_w = (const float*)d_in[2];
  const float* dec_w = (const float*)d_in[3];
  // d_in[4] (dec_b): per-channel constant bias cancels in InstanceNorm mean.
  float* out = (float*)d_out;
  char* ws = (char*)d_ws;

  float* kernbuf = (float*)(ws);                 // 8*9*4096*4   = 0x120000
  short* Ws1     = (short*)(ws + 0x120000);      // 2*36*8192*2  = 0x120000
  short* Ws2     = (short*)(ws + 0x240000);      // 1*36*8192*2  = 0x090000
  float* mr1     = (float*)(ws + 0x2D0000);      // 2048*2*4
  float* mr2     = (float*)(ws + 0x2D4000);      // 1024*2*4
  float* pac     = (float*)(ws + 0x300000);      // 8*256*4096*4 = 0x2000000
  float* ybufB   = (float*)(ws + 0x2300000);     // 8*128*4096*4 = 0x1000000
  // GEMM2 partial ksplit=0 lives in d_out (f32, exact size) -> no extra ws.

  wconv_k<<<(256 * 2304 + 255) / 256, 256, 0, stream>>>(pac_w, Ws1, 256);
  wconv_k<<<(128 * 2304 + 255) / 256, 256, 0, stream>>>(dec_w, Ws2, 128);
  kern_k<<<dim3(64, 8), 256, 0, stream>>>(guide, kernbuf);

  gemm_conv<256, true, false, false><<<dim3(32, 2, 8), 256, 0, stream>>>(
      Ws1, feat, kernbuf, nullptr, pac, nullptr);
  reduce_mv<<<8 * 256, 256, 0, stream>>>(pac, mr1);
  gemm_conv<128, false, true, true><<<dim3(32, 2, 8), 256, 0, stream>>>(
      Ws2, pac, nullptr, mr1, out, ybufB);
  reduce_mv2<<<8 * 128, 256, 0, stream>>>(out, ybufB, mr2);
  finalize2<<<4096, 256, 0, stream>>>(out, ybufB, mr2, out);
}

// Round 8
// 675.018 us; speedup vs baseline: 1.0184x; 1.0184x over previous
//
#include <hip/hip_runtime.h>
#include <hip/hip_bf16.h>

#define IN_EPS 1e-5f

typedef __attribute__((ext_vector_type(8))) short short8;
typedef __attribute__((ext_vector_type(4))) float f32x4;

__device__ __forceinline__ short f2bf(float f) {
  __hip_bfloat16 h = (__hip_bfloat16)f;   // lowers to v_cvt_pk_bf16_f32
  return *(short*)&h;
}

// ---------------------------------------------------------------------------
// Weight conversion: f32 [O][C][3][3] -> bf16 swizzled panel image.
// Panel p = mblk*36 + cb*9 + tap holds [o_local 128][c_local 64], elem at
//   (p<<13) + (ol<<6) + (cl ^ ((ol&7)<<3))
// ---------------------------------------------------------------------------
__global__ void wconv_k(const float* __restrict__ src, short* __restrict__ dst,
                        int O) {
  int idx = blockIdx.x * 256 + threadIdx.x;
  if (idx >= O * 2304) return;
  int o = idx / 2304;
  int r = idx - o * 2304;
  int c = r / 9;
  int k = r - c * 9;
  int mblk = o >> 7, ol = o & 127, cb = c >> 6, cl = c & 63;
  dst[(((size_t)(mblk * 36 + cb * 9 + k)) << 13) + (ol << 6) + (cl ^ ((ol & 7) << 3))]
      = f2bf(src[idx]);
}

// ---------------------------------------------------------------------------
// Adaptive Gaussian kernel: kern[b][k][h][w] = exp(-0.5 * sum_c dg^2)
// lane == image col; neighbors via shfl; no barriers in the channel loop.
// ---------------------------------------------------------------------------
__global__ __launch_bounds__(256) void kern_k(const float* __restrict__ g,
                                              float* __restrict__ kern) {
  int h = blockIdx.x, b = blockIdx.y;
  int t = threadIdx.x, w = t & 63, cg = t >> 6;
  float acc[9];
#pragma unroll
  for (int k = 0; k < 9; ++k) acc[k] = 0.f;
  const float* base = g + (((size_t)b * 256 + (cg << 6)) << 12) + (h << 6) + w;
#pragma unroll 4
  for (int cc = 0; cc < 64; ++cc) {
    const float* gp = base + ((size_t)cc << 12);
    float mid = gp[0];
    float top = (h > 0) ? gp[-64] : 0.f;
    float bot = (h < 63) ? gp[64] : 0.f;
    float rows[3] = {top, mid, bot};
#pragma unroll
    for (int i = 0; i < 3; ++i) {
      float v = rows[i];
      float l = __shfl_up(v, 1);
      float r = __shfl_down(v, 1);
      if (w == 0) l = 0.f;
      if (w == 63) r = 0.f;
      float dl = l - mid, dm = v - mid, dr = r - mid;
      acc[i * 3 + 0] += dl * dl;
      acc[i * 3 + 1] += dm * dm;
      acc[i * 3 + 2] += dr * dr;
    }
  }
  __shared__ float red[4][9][64];
#pragma unroll
  for (int k = 0; k < 9; ++k) red[cg][k][w] = acc[k];
  __syncthreads();
  for (int idx = t; idx < 576; idx += 256) {
    int k = idx >> 6, w2 = idx & 63;
    float s = red[0][k][w2] + red[1][k][w2] + red[2][k][w2] + red[3][k][w2];
    kern[(((size_t)b * 9 + k) << 12) + (h << 6) + w2] = expf(-0.5f * s);
  }
}

// ---------------------------------------------------------------------------
// Implicit-GEMM conv with tap-reuse. BM=128, BN=128 (2 rows), 512 thr/8 waves
// (2M x 4N, wave tile 64x32). K = ncb c-blocks x 9 taps.
// A: LDS (16KB), reg-staged (load before compute, write between barriers).
// B: halo [4 rows][64 cols][64 ch] bf16, staged once per c-block.
//    GEMM1 uses T14 (loads issued before boundary compute, written after);
//    GEMM2 stages serially at its single interior boundary (reg pressure).
// GEMM1 (USE_KERN): per-mf mini-partials p0,p1; acc += kern[tap,px]*p (f32).
// GEMM2 (USE_NORM, KSPLIT): norm+relu fused into staging; K split across
//    blockIdx.y; partials written to outA / outB.
// ---------------------------------------------------------------------------
template <int MTOT, bool USE_KERN, bool USE_NORM, bool KSPLIT>
__global__ __launch_bounds__(512, 4) void gemm_conv(
    const short* __restrict__ Wimg, const float* __restrict__ X,
    const float* __restrict__ Kf, const float* __restrict__ MRin,
    float* __restrict__ outA, float* __restrict__ outB) {
  __shared__ short ldsA[8192];     // [o 128][c 64] swizzled, 16KB
  __shared__ short ldsB[16384];    // [r 4][col 64][c 64] swizzled, 32KB
  __shared__ short ldsS[512];      // side halo cols (-1,64): zeros, 1KB
  __shared__ float klds[USE_KERN ? 1152 : 1];  // kern f32 [9][128]

  const int t = threadIdx.x;
  const int nblk = blockIdx.x, b = blockIdx.z;
  const int mblk = KSPLIT ? 0 : blockIdx.y;
  const int cb0 = KSPLIT ? (int)blockIdx.y * 2 : 0;
  const int ncb = KSPLIT ? 2 : 4;
  float* __restrict__ outp = (KSPLIT && blockIdx.y) ? outB : outA;
  const int h0 = nblk * 2;
  const int lane = t & 63, wid = t >> 6;
  const int wr = wid >> 2, wc = wid & 3;
  const int fr = lane & 15, kg = (lane >> 4) << 3;
  const int scol = t & 63, c8 = (t >> 6) << 3;   // B staging: col, 8-ch base

  f32x4 acc[4][2];
#pragma unroll
  for (int i = 0; i < 4; ++i)
#pragma unroll
    for (int j = 0; j < 2; ++j) acc[i][j] = {0.f, 0.f, 0.f, 0.f};

  float breg[4][8];
  float2 mreg[8];

  auto loadA = [&](int pan, short8* ar) {
    const short* src = Wimg + (((size_t)(mblk * 36 + cb0 * 9 + pan)) << 13) + (t << 3);
    ar[0] = *(const short8*)(src);
    ar[1] = *(const short8*)(src + 4096);
  };
  auto writeA = [&](const short8* ar) {
    *(short8*)&ldsA[t << 3] = ar[0];
    *(short8*)&ldsA[4096 + (t << 3)] = ar[1];
  };
  auto loadBregs = [&](int cbrel) {
    int c0 = ((cb0 + cbrel) << 6) + c8;
    const float* base = X + (((size_t)b * 256 + c0) << 12) + scol;
    if (USE_NORM) {
#pragma unroll
      for (int i = 0; i < 8; ++i)
        mreg[i] = ((const float2*)MRin)[b * 256 + c0 + i];
    }
#pragma unroll
    for (int r = 0; r < 4; ++r) {
      int hr = h0 - 1 + r;
      bool okr = (unsigned)hr < 64u;
      const float* src = base + (hr << 6);
#pragma unroll
      for (int i = 0; i < 8; ++i)
        breg[r][i] = okr ? src[(size_t)i << 12] : 0.f;
    }
  };
  auto writeB = [&]() {
#pragma unroll
    for (int r = 0; r < 4; ++r) {
      short8 pk;
#pragma unroll
      for (int i = 0; i < 8; ++i) {
        float x = breg[r][i];
        if (USE_NORM) x = fmaxf((x - mreg[i].x) * mreg[i].y, 0.f);
        pk[i] = f2bf(x);
      }
      *(short8*)&ldsB[(((r << 6) + scol) << 6) + (c8 ^ ((scol & 7) << 3))] = pk;
    }
  };
  auto computeTap = [&](int tap) {
    const int di = tap / 3 - 1, dj = tap % 3 - 1;
    short8 b2[2][2];
#pragma unroll
    for (int ks = 0; ks < 2; ++ks) {
      int kb = (ks << 5) + kg;
#pragma unroll
      for (int nf = 0; nf < 2; ++nf) {
        int px = (wc << 5) + (nf << 4) + fr;
        int rr2 = (px >> 6) + di + 1;
        int wcol = (px & 63) + dj;
        int kbs = kb ^ ((wcol & 7) << 3);
        const short* pm = &ldsB[(((rr2 << 6) + wcol) << 6) + kbs];
        const short* ps = &ldsS[(((rr2 << 1) + (wcol == 64)) << 6) + kbs];
        b2[ks][nf] = *(const short8*)(((unsigned)wcol < 64u) ? pm : ps);
      }
    }
    float kq0, kq1;
    if (USE_KERN) {
      kq0 = klds[tap * 128 + (wc << 5) + fr];
      kq1 = klds[tap * 128 + (wc << 5) + 16 + fr];
    }
#pragma unroll
    for (int mf = 0; mf < 4; ++mf) {
      int rr = (wr << 6) + (mf << 4) + fr;
      int xr = (rr & 7) << 3;
      short8 A0 = *(const short8*)&ldsA[(rr << 6) + (kg ^ xr)];
      short8 A1 = *(const short8*)&ldsA[(rr << 6) + ((32 + kg) ^ xr)];
      __builtin_amdgcn_s_setprio(1);
      if (USE_KERN) {
        f32x4 p0 = {0.f, 0.f, 0.f, 0.f}, p1 = {0.f, 0.f, 0.f, 0.f};
        p0 = __builtin_amdgcn_mfma_f32_16x16x32_bf16(A0, b2[0][0], p0, 0, 0, 0);
        p1 = __builtin_amdgcn_mfma_f32_16x16x32_bf16(A0, b2[0][1], p1, 0, 0, 0);
        p0 = __builtin_amdgcn_mfma_f32_16x16x32_bf16(A1, b2[1][0], p0, 0, 0, 0);
        p1 = __builtin_amdgcn_mfma_f32_16x16x32_bf16(A1, b2[1][1], p1, 0, 0, 0);
        __builtin_amdgcn_s_setprio(0);
#pragma unroll
        for (int j = 0; j < 4; ++j) {
          acc[mf][0][j] += kq0 * p0[j];
          acc[mf][1][j] += kq1 * p1[j];
        }
      } else {
        acc[mf][0] = __builtin_amdgcn_mfma_f32_16x16x32_bf16(A0, b2[0][0], acc[mf][0], 0, 0, 0);
        acc[mf][1] = __builtin_amdgcn_mfma_f32_16x16x32_bf16(A0, b2[0][1], acc[mf][1], 0, 0, 0);
        acc[mf][0] = __builtin_amdgcn_mfma_f32_16x16x32_bf16(A1, b2[1][0], acc[mf][0], 0, 0, 0);
        acc[mf][1] = __builtin_amdgcn_mfma_f32_16x16x32_bf16(A1, b2[1][1], acc[mf][1], 0, 0, 0);
        __builtin_amdgcn_s_setprio(0);
      }
    }
  };

  // ---- prologue ----
  if (t < 64) {
    short8 z = {0, 0, 0, 0, 0, 0, 0, 0};
    *(short8*)&ldsS[t << 3] = z;
  }
  if (USE_KERN) {
    for (int idx = t; idx < 1152; idx += 512) {
      int tap = idx >> 7, px = idx & 127;
      klds[idx] = Kf[(((size_t)b * 9 + tap) << 12) +
                     ((h0 + (px >> 6)) << 6) + (px & 63)];
    }
  }
  {
    short8 ar[2];
    loadA(0, ar);
    loadBregs(0);
    writeA(ar);
    writeB();
  }
  __syncthreads();

  // ---- main loop: ncb c-blocks x 9 taps ----
  const int nt = ncb * 9;
  for (int cbrel = 0; cbrel < ncb; ++cbrel) {
    for (int tap = 0; tap < 9; ++tap) {
      int pan = cbrel * 9 + tap;
      bool more = (pan + 1) < nt;
      bool lastTap = (tap == 8);
      short8 ar[2];
      if (more && !lastTap) loadA(pan + 1, ar);
      if (USE_KERN && more && lastTap) loadBregs(cbrel + 1);  // T14: issue early
      computeTap(tap);
      __syncthreads();                     // all waves done reading A/B
      if (more) {
        if (!lastTap) {
          writeA(ar);
        } else if (USE_KERN) {
          writeB();                        // breg dies here
          loadA(pan + 1, ar);              // brief exposed load (3x total)
          writeA(ar);
        } else {
          loadBregs(cbrel + 1);            // serial boundary staging (GEMM2)
          writeB();
          loadA(pan + 1, ar);
          writeA(ar);
        }
        __syncthreads();                   // publish A (+B)
      }
    }
  }

  // ---- epilogue ----
  const int row4 = (lane >> 4) << 2;
#pragma unroll
  for (int mf = 0; mf < 4; ++mf) {
    int o = (mblk << 7) + (wr << 6) + (mf << 4) + row4;
    size_t ob = (((size_t)b * MTOT + o) << 12) + (nblk << 7) + (wc << 5) + fr;
#pragma unroll
    for (int nf = 0; nf < 2; ++nf) {
      f32x4 v = acc[mf][nf];
      size_t oo = ob + (nf << 4);
      outp[oo] = v[0];
      outp[oo + 4096] = v[1];
      outp[oo + 8192] = v[2];
      outp[oo + 12288] = v[3];
    }
  }
}

// ---------------------------------------------------------------------------
// per-(b,ch) mean / rstd over 4096 pixels (single input)
// ---------------------------------------------------------------------------
__global__ __launch_bounds__(256) void reduce_mv(const float* __restrict__ x,
                                                 float* __restrict__ mr) {
  int bc = blockIdx.x, t = threadIdx.x;
  const float4* xp = (const float4*)(x + ((size_t)bc << 12));
  float s = 0.f, s2 = 0.f;
  for (int i = t; i < 1024; i += 256) {
    float4 v = xp[i];
    s += v.x + v.y + v.z + v.w;
    s2 += v.x * v.x + v.y * v.y + v.z * v.z + v.w * v.w;
  }
#pragma unroll
  for (int off = 32; off; off >>= 1) {
    s += __shfl_down(s, off);
    s2 += __shfl_down(s2, off);
  }
  __shared__ float ls[4], ls2[4];
  int wid = t >> 6, lane = t & 63;
  if (!lane) { ls[wid] = s; ls2[wid] = s2; }
  __syncthreads();
  if (!t) {
    s = ls[0] + ls[1] + ls[2] + ls[3];
    s2 = ls2[0] + ls2[1] + ls2[2] + ls2[3];
    float m = s * (1.f / 4096.f);
    float var = s2 * (1.f / 4096.f) - m * m;
    mr[2 * bc] = m;
    mr[2 * bc + 1] = rsqrtf(fmaxf(var, 0.f) + IN_EPS);
  }
}

// ---------------------------------------------------------------------------
// per-(b,ch) mean / rstd over 4096 pixels of (a + b) (split-K partials)
// ---------------------------------------------------------------------------
__global__ __launch_bounds__(256) void reduce_mv2(const float* __restrict__ xa,
                                                  const float* __restrict__ xb,
                                                  float* __restrict__ mr) {
  int bc = blockIdx.x, t = threadIdx.x;
  const float4* ap = (const float4*)(xa + ((size_t)bc << 12));
  const float4* bp = (const float4*)(xb + ((size_t)bc << 12));
  float s = 0.f, s2 = 0.f;
  for (int i = t; i < 1024; i += 256) {
    float4 va = ap[i], vb = bp[i];
    float x0 = va.x + vb.x, x1 = va.y + vb.y, x2 = va.z + vb.z, x3 = va.w + vb.w;
    s += x0 + x1 + x2 + x3;
    s2 += x0 * x0 + x1 * x1 + x2 * x2 + x3 * x3;
  }
#pragma unroll
  for (int off = 32; off; off >>= 1) {
    s += __shfl_down(s, off);
    s2 += __shfl_down(s2, off);
  }
  __shared__ float ls[4], ls2[4];
  int wid = t >> 6, lane = t & 63;
  if (!lane) { ls[wid] = s; ls2[wid] = s2; }
  __syncthreads();
  if (!t) {
    s = ls[0] + ls[1] + ls[2] + ls[3];
    s2 = ls2[0] + ls2[1] + ls2[2] + ls2[3];
    float m = s * (1.f / 4096.f);
    float var = s2 * (1.f / 4096.f) - m * m;
    mr[2 * bc] = m;
    mr[2 * bc + 1] = rsqrtf(fmaxf(var, 0.f) + IN_EPS);
  }
}

// ---------------------------------------------------------------------------
// out = relu(((a+b) - mean)*rstd); a aliases out (read-before-write per elem)
// ---------------------------------------------------------------------------
__global__ __launch_bounds__(256) void finalize2(const float* __restrict__ ya,
                                                 const float* __restrict__ yb,
                                                 const float* __restrict__ mr,
                                                 float* __restrict__ out) {
  int i = blockIdx.x * 256 + threadIdx.x;
  int bc = i >> 10;
  float m = mr[2 * bc], r = mr[2 * bc + 1];
  float4 va = ((const float4*)ya)[i];
  float4 vb = ((const float4*)yb)[i];
  float4 v;
  v.x = fmaxf((va.x + vb.x - m) * r, 0.f);
  v.y = fmaxf((va.y + vb.y - m) * r, 0.f);
  v.z = fmaxf((va.z + vb.z - m) * r, 0.f);
  v.w = fmaxf((va.w + vb.w - m) * r, 0.f);
  ((float4*)out)[i] = v;
}

extern "C" void kernel_launch(void* const* d_in, const int* in_sizes, int n_in,
                              void* d_out, int out_size, void* d_ws,
                              size_t ws_size, hipStream_t stream) {
  (void)in_sizes; (void)n_in; (void)out_size; (void)ws_size;
  const float* feat  = (const float*)d_in[0];
  const float* guide = (const float*)d_in[1];
  const float* pac_w = (const float*)d_in[2];
  const float* dec_w = (const float*)d_in[3];
  // d_in[4] (dec_b): per-channel constant bias cancels in InstanceNorm mean.
  float* out = (float*)d_out;
  char* ws = (char*)d_ws;

  float* kernbuf = (float*)(ws);                 // 8*9*4096*4   = 0x120000
  short* Ws1     = (short*)(ws + 0x120000);      // 2*36*8192*2  = 0x120000
  short* Ws2     = (short*)(ws + 0x240000);      // 1*36*8192*2  = 0x090000
  float* mr1     = (float*)(ws + 0x2D0000);      // 2048*2*4
  float* mr2     = (float*)(ws + 0x2D4000);      // 1024*2*4
  float* pac     = (float*)(ws + 0x300000);      // 8*256*4096*4 = 0x2000000
  float* ybufB   = (float*)(ws + 0x2300000);     // 8*128*4096*4 = 0x1000000
  // GEMM2 partial ksplit=0 lives in d_out (f32, exact size) -> no extra ws.

  wconv_k<<<(256 * 2304 + 255) / 256, 256, 0, stream>>>(pac_w, Ws1, 256);
  wconv_k<<<(128 * 2304 + 255) / 256, 256, 0, stream>>>(dec_w, Ws2, 128);
  kern_k<<<dim3(64, 8), 256, 0, stream>>>(guide, kernbuf);

  gemm_conv<256, true, false, false><<<dim3(32, 2, 8), 512, 0, stream>>>(
      Ws1, feat, kernbuf, nullptr, pac, nullptr);
  reduce_mv<<<8 * 256, 256, 0, stream>>>(pac, mr1);
  gemm_conv<128, false, true, true><<<dim3(32, 2, 8), 512, 0, stream>>>(
      Ws2, pac, nullptr, mr1, out, ybufB);
  reduce_mv2<<<8 * 128, 256, 0, stream>>>(out, ybufB, mr2);
  finalize2<<<4096, 256, 0, stream>>>(out, ybufB, mr2, out);
}

// Round 9
// 149.569 us; speedup vs baseline: 4.5962x; 4.5131x over previous
//
#include <hip/hip_runtime.h>
#include <hip/hip_bf16.h>

#define IN_EPS 1e-5f

typedef __attribute__((ext_vector_type(8))) short short8;
typedef __attribute__((ext_vector_type(4))) float f32x4;

__device__ __forceinline__ short f2bf(float f) {
  __hip_bfloat16 h = (__hip_bfloat16)f;   // lowers to v_cvt_pk_bf16_f32
  return *(short*)&h;
}
__device__ __forceinline__ float bf2f(short s) {
  union { unsigned u; float f; } x;
  x.u = ((unsigned)(unsigned short)s) << 16;
  return x.f;
}

// ---------------------------------------------------------------------------
// Weight conversion: f32 [O][C][3][3] -> bf16 swizzled panel image.
// Panel p = mblk*36 + cb*9 + tap holds [o_local 128][c_local 64], elem at
//   (p<<13) + (ol<<6) + (cl ^ ((ol&7)<<3))
// ---------------------------------------------------------------------------
__global__ void wconv_k(const float* __restrict__ src, short* __restrict__ dst,
                        int O) {
  int idx = blockIdx.x * 256 + threadIdx.x;
  if (idx >= O * 2304) return;
  int o = idx / 2304;
  int r = idx - o * 2304;
  int c = r / 9;
  int k = r - c * 9;
  int mblk = o >> 7, ol = o & 127, cb = c >> 6, cl = c & 63;
  dst[(((size_t)(mblk * 36 + cb * 9 + k)) << 13) + (ol << 6) + (cl ^ ((ol & 7) << 3))]
      = f2bf(src[idx]);
}

// ---------------------------------------------------------------------------
// Adaptive Gaussian kernel: kern[b][k][h][w] = exp(-0.5 * sum_c dg^2)
// lane == image col; neighbors via shfl; no barriers in the channel loop.
// ---------------------------------------------------------------------------
__global__ __launch_bounds__(256) void kern_k(const float* __restrict__ g,
                                              float* __restrict__ kern) {
  int h = blockIdx.x, b = blockIdx.y;
  int t = threadIdx.x, w = t & 63, cg = t >> 6;
  float acc[9];
#pragma unroll
  for (int k = 0; k < 9; ++k) acc[k] = 0.f;
  const float* base = g + (((size_t)b * 256 + (cg << 6)) << 12) + (h << 6) + w;
#pragma unroll 4
  for (int cc = 0; cc < 64; ++cc) {
    const float* gp = base + ((size_t)cc << 12);
    float mid = gp[0];
    float top = (h > 0) ? gp[-64] : 0.f;
    float bot = (h < 63) ? gp[64] : 0.f;
    float rows[3] = {top, mid, bot};
#pragma unroll
    for (int i = 0; i < 3; ++i) {
      float v = rows[i];
      float l = __shfl_up(v, 1);
      float r = __shfl_down(v, 1);
      if (w == 0) l = 0.f;
      if (w == 63) r = 0.f;
      float dl = l - mid, dm = v - mid, dr = r - mid;
      acc[i * 3 + 0] += dl * dl;
      acc[i * 3 + 1] += dm * dm;
      acc[i * 3 + 2] += dr * dr;
    }
  }
  __shared__ float red[4][9][64];
#pragma unroll
  for (int k = 0; k < 9; ++k) red[cg][k][w] = acc[k];
  __syncthreads();
  for (int idx = t; idx < 576; idx += 256) {
    int k = idx >> 6, w2 = idx & 63;
    float s = red[0][k][w2] + red[1][k][w2] + red[2][k][w2] + red[3][k][w2];
    kern[(((size_t)b * 9 + k) << 12) + (h << 6) + w2] = expf(-0.5f * s);
  }
}

// ---------------------------------------------------------------------------
// Implicit-GEMM conv with tap-reuse (R4 structure + A double-buffer).
// BM=128, BN=128 (2 rows), 512 thr / 8 waves (2M x 4N, wave tile 64x32).
// K = ncb c-blocks x 9 taps. A: LDS dbuf, reg-staged; write into the idle
// buffer pre-barrier -> ONE barrier per non-boundary step.
// B: halo [4 rows][64 cols][64 ch] bf16, staged once per c-block
//    (GEMM1: T14 issue-early; GEMM2: serial at its single boundary).
// GEMM1 (USE_KERN): kern[tap,px] frag-folded into B fragment (bf16).
// GEMM2 (USE_NORM, KSPLIT): norm+relu fused into staging; K split across
//    blockIdx.y; partials written to outA / outB.
// ---------------------------------------------------------------------------
template <int MTOT, bool USE_KERN, bool USE_NORM, bool KSPLIT>
__global__ __launch_bounds__(512, 4) void gemm_conv(
    const short* __restrict__ Wimg, const float* __restrict__ X,
    const float* __restrict__ Kf, const float* __restrict__ MRin,
    float* __restrict__ outA, float* __restrict__ outB) {
  __shared__ short ldsA[2][8192];  // [o 128][c 64] swizzled, dbuf, 32KB
  __shared__ short ldsB[16384];    // [r 4][col 64][c 64] swizzled, 32KB
  __shared__ short ldsS[512];      // side halo cols (-1,64): zeros, 1KB
  __shared__ float klds[USE_KERN ? 1152 : 1];  // kern f32 [9][128]

  const int t = threadIdx.x;
  const int nblk = blockIdx.x, b = blockIdx.z;
  const int mblk = KSPLIT ? 0 : blockIdx.y;
  const int cb0 = KSPLIT ? (int)blockIdx.y * 2 : 0;
  const int ncb = KSPLIT ? 2 : 4;
  float* __restrict__ outp = (KSPLIT && blockIdx.y) ? outB : outA;
  const int h0 = nblk * 2;
  const int lane = t & 63, wid = t >> 6;
  const int wr = wid >> 2, wc = wid & 3;
  const int fr = lane & 15, kg = (lane >> 4) << 3;
  const int scol = t & 63, c8 = (t >> 6) << 3;   // B staging: col, 8-ch base

  f32x4 acc[4][2];
#pragma unroll
  for (int i = 0; i < 4; ++i)
#pragma unroll
    for (int j = 0; j < 2; ++j) acc[i][j] = {0.f, 0.f, 0.f, 0.f};

  float breg[4][8];
  float2 mreg[8];

  auto loadA = [&](int pan, short8* ar) {
    const short* src =
        Wimg + (((size_t)(mblk * 36 + cb0 * 9 + pan)) << 13) + (t << 3);
    ar[0] = *(const short8*)(src);
    ar[1] = *(const short8*)(src + 4096);
  };
  auto writeA = [&](const short8* ar, int buf) {
    *(short8*)&ldsA[buf][t << 3] = ar[0];
    *(short8*)&ldsA[buf][4096 + (t << 3)] = ar[1];
  };
  auto loadBregs = [&](int cbrel) {
    int c0 = ((cb0 + cbrel) << 6) + c8;
    const float* base = X + (((size_t)b * 256 + c0) << 12) + scol;
    if (USE_NORM) {
#pragma unroll
      for (int i = 0; i < 8; ++i)
        mreg[i] = ((const float2*)MRin)[b * 256 + c0 + i];
    }
#pragma unroll
    for (int r = 0; r < 4; ++r) {
      int hr = h0 - 1 + r;
      bool okr = (unsigned)hr < 64u;
      const float* src = base + (hr << 6);
#pragma unroll
      for (int i = 0; i < 8; ++i)
        breg[r][i] = okr ? src[(size_t)i << 12] : 0.f;
    }
  };
  auto writeB = [&]() {
#pragma unroll
    for (int r = 0; r < 4; ++r) {
      short8 pk;
#pragma unroll
      for (int i = 0; i < 8; ++i) {
        float x = breg[r][i];
        if (USE_NORM) x = fmaxf((x - mreg[i].x) * mreg[i].y, 0.f);
        pk[i] = f2bf(x);
      }
      *(short8*)&ldsB[(((r << 6) + scol) << 6) + (c8 ^ ((scol & 7) << 3))] = pk;
    }
  };
  auto computeTap = [&](int tap, int buf) {
    const int di = tap / 3 - 1, dj = tap % 3 - 1;
    float kfv[2];
    if (USE_KERN) {
      kfv[0] = klds[tap * 128 + (wc << 5) + fr];
      kfv[1] = klds[tap * 128 + (wc << 5) + 16 + fr];
    }
#pragma unroll
    for (int ks = 0; ks < 2; ++ks) {
      int kb = (ks << 5) + kg;
      short8 a4[4], b2[2];
#pragma unroll
      for (int mf = 0; mf < 4; ++mf) {
        int rr = (wr << 6) + (mf << 4) + fr;
        a4[mf] = *(const short8*)&ldsA[buf][(rr << 6) + (kb ^ ((rr & 7) << 3))];
      }
#pragma unroll
      for (int nf = 0; nf < 2; ++nf) {
        int px = (wc << 5) + (nf << 4) + fr;
        int rr2 = (px >> 6) + di + 1;
        int wcol = (px & 63) + dj;
        int kbs = kb ^ ((wcol & 7) << 3);
        const short* pm = &ldsB[(((rr2 << 6) + wcol) << 6) + kbs];
        const short* ps = &ldsS[(((rr2 << 1) + (wcol == 64)) << 6) + kbs];
        short8 bb = *(const short8*)(((unsigned)wcol < 64u) ? pm : ps);
        if (USE_KERN) {
#pragma unroll
          for (int i = 0; i < 8; ++i) bb[i] = f2bf(bf2f(bb[i]) * kfv[nf]);
        }
        b2[nf] = bb;
      }
#pragma unroll
      for (int mf = 0; mf < 4; ++mf)
#pragma unroll
        for (int nf = 0; nf < 2; ++nf)
          acc[mf][nf] = __builtin_amdgcn_mfma_f32_16x16x32_bf16(
              a4[mf], b2[nf], acc[mf][nf], 0, 0, 0);
    }
  };

  // ---- prologue ----
  if (t < 64) {
    short8 z = {0, 0, 0, 0, 0, 0, 0, 0};
    *(short8*)&ldsS[t << 3] = z;
  }
  if (USE_KERN) {
    for (int idx = t; idx < 1152; idx += 512) {
      int tap = idx >> 7, px = idx & 127;
      klds[idx] = Kf[(((size_t)b * 9 + tap) << 12) +
                     ((h0 + (px >> 6)) << 6) + (px & 63)];
    }
  }
  {
    short8 ar[2];
    loadA(0, ar);
    loadBregs(0);
    writeA(ar, 0);
    writeB();
  }
  __syncthreads();

  // ---- main loop: ncb c-blocks x 9 taps; 1 barrier per interior step ----
  const int nt = ncb * 9;
  int tap = 0, cbrel = 0;
  for (int pan = 0; pan < nt; ++pan) {
    int buf = pan & 1;
    bool more = (pan + 1) < nt;
    bool lastTap = (tap == 8);
    short8 ar[2];
    if (more) loadA(pan + 1, ar);                       // overlaps compute
    if (USE_KERN && more && lastTap) loadBregs(cbrel + 1);  // T14 issue-early
    computeTap(tap, buf);
    if (more && lastTap) {
      __syncthreads();                 // B readers done
      if (!USE_NORM) {
        writeB();
      } else {
        loadBregs(cbrel + 1);          // serial staging (register safety)
        writeB();
      }
      writeA(ar, buf ^ 1);
      __syncthreads();                 // publish A+B
    } else if (more) {
      writeA(ar, buf ^ 1);             // idle buffer: no pre-write barrier
      __syncthreads();                 // publish A
    }
    if (++tap == 9) { tap = 0; ++cbrel; }
  }

  // ---- epilogue ----
  const int row4 = (lane >> 4) << 2;
#pragma unroll
  for (int mf = 0; mf < 4; ++mf) {
    int o = (mblk << 7) + (wr << 6) + (mf << 4) + row4;
    size_t ob = (((size_t)b * MTOT + o) << 12) + (nblk << 7) + (wc << 5) + fr;
#pragma unroll
    for (int nf = 0; nf < 2; ++nf) {
      f32x4 v = acc[mf][nf];
      size_t oo = ob + (nf << 4);
      outp[oo] = v[0];
      outp[oo + 4096] = v[1];
      outp[oo + 8192] = v[2];
      outp[oo + 12288] = v[3];
    }
  }
}

// ---------------------------------------------------------------------------
// per-(b,ch) mean / rstd over 4096 pixels (single input)
// ---------------------------------------------------------------------------
__global__ __launch_bounds__(256) void reduce_mv(const float* __restrict__ x,
                                                 float* __restrict__ mr) {
  int bc = blockIdx.x, t = threadIdx.x;
  const float4* xp = (const float4*)(x + ((size_t)bc << 12));
  float s = 0.f, s2 = 0.f;
  for (int i = t; i < 1024; i += 256) {
    float4 v = xp[i];
    s += v.x + v.y + v.z + v.w;
    s2 += v.x * v.x + v.y * v.y + v.z * v.z + v.w * v.w;
  }
#pragma unroll
  for (int off = 32; off; off >>= 1) {
    s += __shfl_down(s, off);
    s2 += __shfl_down(s2, off);
  }
  __shared__ float ls[4], ls2[4];
  int wid = t >> 6, lane = t & 63;
  if (!lane) { ls[wid] = s; ls2[wid] = s2; }
  __syncthreads();
  if (!t) {
    s = ls[0] + ls[1] + ls[2] + ls[3];
    s2 = ls2[0] + ls2[1] + ls2[2] + ls2[3];
    float m = s * (1.f / 4096.f);
    float var = s2 * (1.f / 4096.f) - m * m;
    mr[2 * bc] = m;
    mr[2 * bc + 1] = rsqrtf(fmaxf(var, 0.f) + IN_EPS);
  }
}

// ---------------------------------------------------------------------------
// per-(b,ch) mean / rstd over 4096 pixels of (a + b) (split-K partials)
// ---------------------------------------------------------------------------
__global__ __launch_bounds__(256) void reduce_mv2(const float* __restrict__ xa,
                                                  const float* __restrict__ xb,
                                                  float* __restrict__ mr) {
  int bc = blockIdx.x, t = threadIdx.x;
  const float4* ap = (const float4*)(xa + ((size_t)bc << 12));
  const float4* bp = (const float4*)(xb + ((size_t)bc << 12));
  float s = 0.f, s2 = 0.f;
  for (int i = t; i < 1024; i += 256) {
    float4 va = ap[i], vb = bp[i];
    float x0 = va.x + vb.x, x1 = va.y + vb.y, x2 = va.z + vb.z, x3 = va.w + vb.w;
    s += x0 + x1 + x2 + x3;
    s2 += x0 * x0 + x1 * x1 + x2 * x2 + x3 * x3;
  }
#pragma unroll
  for (int off = 32; off; off >>= 1) {
    s += __shfl_down(s, off);
    s2 += __shfl_down(s2, off);
  }
  __shared__ float ls[4], ls2[4];
  int wid = t >> 6, lane = t & 63;
  if (!lane) { ls[wid] = s; ls2[wid] = s2; }
  __syncthreads();
  if (!t) {
    s = ls[0] + ls[1] + ls[2] + ls[3];
    s2 = ls2[0] + ls2[1] + ls2[2] + ls2[3];
    float m = s * (1.f / 4096.f);
    float var = s2 * (1.f / 4096.f) - m * m;
    mr[2 * bc] = m;
    mr[2 * bc + 1] = rsqrtf(fmaxf(var, 0.f) + IN_EPS);
  }
}

// ---------------------------------------------------------------------------
// out = relu(((a+b) - mean)*rstd); a aliases out (read-before-write per elem)
// ---------------------------------------------------------------------------
__global__ __launch_bounds__(256) void finalize2(const float* __restrict__ ya,
                                                 const float* __restrict__ yb,
                                                 const float* __restrict__ mr,
                                                 float* __restrict__ out) {
  int i = blockIdx.x * 256 + threadIdx.x;
  int bc = i >> 10;
  float m = mr[2 * bc], r = mr[2 * bc + 1];
  float4 va = ((const float4*)ya)[i];
  float4 vb = ((const float4*)yb)[i];
  float4 v;
  v.x = fmaxf((va.x + vb.x - m) * r, 0.f);
  v.y = fmaxf((va.y + vb.y - m) * r, 0.f);
  v.z = fmaxf((va.z + vb.z - m) * r, 0.f);
  v.w = fmaxf((va.w + vb.w - m) * r, 0.f);
  ((float4*)out)[i] = v;
}

extern "C" void kernel_launch(void* const* d_in, const int* in_sizes, int n_in,
                              void* d_out, int out_size, void* d_ws,
                              size_t ws_size, hipStream_t stream) {
  (void)in_sizes; (void)n_in; (void)out_size; (void)ws_size;
  const float* feat  = (const float*)d_in[0];
  const float* guide = (const float*)d_in[1];
  const float* pac_w = (const float*)d_in[2];
  const float* dec_w = (const float*)d_in[3];
  // d_in[4] (dec_b): per-channel constant bias cancels in InstanceNorm mean.
  float* out = (float*)d_out;
  char* ws = (char*)d_ws;

  float* kernbuf = (float*)(ws);                 // 8*9*4096*4   = 0x120000
  short* Ws1     = (short*)(ws + 0x120000);      // 2*36*8192*2  = 0x120000
  short* Ws2     = (short*)(ws + 0x240000);      // 1*36*8192*2  = 0x090000
  float* mr1     = (float*)(ws + 0x2D0000);      // 2048*2*4
  float* mr2     = (float*)(ws + 0x2D4000);      // 1024*2*4
  float* pac     = (float*)(ws + 0x300000);      // 8*256*4096*4 = 0x2000000
  float* ybufB   = (float*)(ws + 0x2300000);     // 8*128*4096*4 = 0x1000000
  // GEMM2 partial ksplit=0 lives in d_out (f32, exact size) -> no extra ws.

  wconv_k<<<(256 * 2304 + 255) / 256, 256, 0, stream>>>(pac_w, Ws1, 256);
  wconv_k<<<(128 * 2304 + 255) / 256, 256, 0, stream>>>(dec_w, Ws2, 128);
  kern_k<<<dim3(64, 8), 256, 0, stream>>>(guide, kernbuf);

  gemm_conv<256, true, false, false><<<dim3(32, 2, 8), 512, 0, stream>>>(
      Ws1, feat, kernbuf, nullptr, pac, nullptr);
  reduce_mv<<<8 * 256, 256, 0, stream>>>(pac, mr1);
  gemm_conv<128, false, true, true><<<dim3(32, 2, 8), 512, 0, stream>>>(
      Ws2, pac, nullptr, mr1, out, ybufB);
  reduce_mv2<<<8 * 128, 256, 0, stream>>>(out, ybufB, mr2);
  finalize2<<<4096, 256, 0, stream>>>(out, ybufB, mr2, out);
}